// Round 1
// baseline (348.200 us; speedup 1.0000x reference)
//
#include <hip/hip_runtime.h>
#include <math.h>

#define DDIM 4096
#define NTOK 8192

// Swizzled LDS address: 4 pad words per 64 -> preserves float4 alignment,
// <=2-way bank aliasing for all three access phases (free on gfx950).
__device__ __forceinline__ int lad(int i) { return i + ((i >> 6) << 2); }

// 4 butterfly stages over the 4-bit register index (one FWHT "phase").
__device__ __forceinline__ void fwht16(float v[16]) {
#pragma unroll
  for (int m = 1; m < 16; m <<= 1) {
#pragma unroll
    for (int a = 0; a < 16; ++a) {
      if ((a & m) == 0) {
        float p = v[a];
        float q = v[a ^ m];
        v[a] = p + q;
        v[a ^ m] = p - q;
      }
    }
  }
}

__global__ __launch_bounds__(256) void whvi_fwht_kernel(
    const float* __restrict__ x,
    const float* __restrict__ s1,
    const float* __restrict__ s2,
    const float* __restrict__ g_mu,
    const float* __restrict__ g_rho,
    const float* __restrict__ eps,
    float* __restrict__ out)
{
  __shared__ __align__(16) float lds[4096 + 256];  // lad(4095)=4347 < 4352

  const int t = threadIdx.x;
  const size_t row = (size_t)blockIdx.x;
  float v[16];

  // ---- load phase A (i = 16t + j), multiply by s2; coalesced float4 ----
  const float4* x4  = (const float4*)(x + row * DDIM);
  const float4* s24 = (const float4*)s2;
#pragma unroll
  for (int q = 0; q < 4; ++q) {
    float4 a = x4[t * 4 + q];
    float4 b = s24[t * 4 + q];
    v[4 * q + 0] = a.x * b.x;
    v[4 * q + 1] = a.y * b.y;
    v[4 * q + 2] = a.z * b.z;
    v[4 * q + 3] = a.w * b.w;
  }
  fwht16(v);  // FWHT1 bits 0-3

  // ---- exchange A -> B ----
#pragma unroll
  for (int q = 0; q < 4; ++q) {
    int i = t * 16 + q * 4;
    float4 w = make_float4(v[4 * q], v[4 * q + 1], v[4 * q + 2], v[4 * q + 3]);
    *(float4*)&lds[lad(i)] = w;  // ds_write_b128, conflict-free
  }
  __syncthreads();
  const int bbase = (t >> 4) * 256 + (t & 15);  // phase B: i = bbase + 16j
#pragma unroll
  for (int j = 0; j < 16; ++j) v[j] = lds[lad(bbase + j * 16)];
  fwht16(v);  // FWHT1 bits 4-7

  // ---- exchange B -> C ----
  __syncthreads();
#pragma unroll
  for (int j = 0; j < 16; ++j) lds[lad(bbase + j * 16)] = v[j];
  __syncthreads();
#pragma unroll
  for (int j = 0; j < 16; ++j) v[j] = lds[lad(j * 256 + t)];  // phase C: i = 256j + t
  fwht16(v);  // FWHT1 bits 8-11  -> FWHT1 complete

  // ---- g_tilde = g_mu + softplus(g_rho)*eps, elementwise (phase C layout) ----
#pragma unroll
  for (int j = 0; j < 16; ++j) {
    int i = j * 256 + t;
    float r = g_rho[i];
    float sp = (r > 0.0f) ? (r + log1pf(__expf(-r))) : log1pf(__expf(r));
    float g = g_mu[i] + sp * eps[i];
    v[j] *= g;
  }

  fwht16(v);  // FWHT2 bits 8-11

  // ---- exchange C -> B ----
  __syncthreads();
#pragma unroll
  for (int j = 0; j < 16; ++j) lds[lad(j * 256 + t)] = v[j];
  __syncthreads();
#pragma unroll
  for (int j = 0; j < 16; ++j) v[j] = lds[lad(bbase + j * 16)];
  fwht16(v);  // FWHT2 bits 4-7

  // ---- exchange B -> A ----
  __syncthreads();
#pragma unroll
  for (int j = 0; j < 16; ++j) lds[lad(bbase + j * 16)] = v[j];
  __syncthreads();
#pragma unroll
  for (int q = 0; q < 4; ++q) {
    float4 w = *(const float4*)&lds[lad(t * 16 + q * 4)];  // ds_read_b128
    v[4 * q + 0] = w.x;
    v[4 * q + 1] = w.y;
    v[4 * q + 2] = w.z;
    v[4 * q + 3] = w.w;
  }
  fwht16(v);  // FWHT2 bits 0-3

  // ---- multiply by s1, store (coalesced float4) ----
  const float4* s14 = (const float4*)s1;
  float4* out4 = (float4*)(out + row * DDIM);
#pragma unroll
  for (int q = 0; q < 4; ++q) {
    float4 b = s14[t * 4 + q];
    float4 w;
    w.x = v[4 * q + 0] * b.x;
    w.y = v[4 * q + 1] * b.y;
    w.z = v[4 * q + 2] * b.z;
    w.w = v[4 * q + 3] * b.w;
    out4[t * 4 + q] = w;
  }
}

extern "C" void kernel_launch(void* const* d_in, const int* in_sizes, int n_in,
                              void* d_out, int out_size, void* d_ws, size_t ws_size,
                              hipStream_t stream) {
  // setup_inputs order: x, s1, s2, g_mu, g_rho, eps, H (H unused: we use FWHT)
  const float* x     = (const float*)d_in[0];
  const float* s1    = (const float*)d_in[1];
  const float* s2    = (const float*)d_in[2];
  const float* g_mu  = (const float*)d_in[3];
  const float* g_rho = (const float*)d_in[4];
  const float* eps   = (const float*)d_in[5];
  float* out = (float*)d_out;

  whvi_fwht_kernel<<<NTOK, 256, 0, stream>>>(x, s1, s2, g_mu, g_rho, eps, out);
}

// Round 2
// 276.064 us; speedup vs baseline: 1.2613x; 1.2613x over previous
//
#include <hip/hip_runtime.h>
#include <math.h>

#define DDIM 4096
#define NTOK 8192
#define RPB  2            // rows per block (1 wave per row)
#define LROW 4160         // 4096 + 16*4 pad words; addr(i) = i + 4*(i>>8)

// FWHT over 64 elements held as float2 w[32].
// Stage order: intra-float2 bit first (scalar), then 5 stages over the
// float2 index (float2 ops -> v_pk_add_f32). All stages commute.
__device__ __forceinline__ void fwht64(float2 w[32]) {
#pragma unroll
  for (int k = 0; k < 32; ++k) {
    float p = w[k].x, q = w[k].y;
    w[k].x = p + q;
    w[k].y = p - q;
  }
#pragma unroll
  for (int m = 1; m < 32; m <<= 1) {
#pragma unroll
    for (int k = 0; k < 32; ++k) {
      if ((k & m) == 0) {
        float2 a = w[k], b = w[k ^ m];
        w[k].x     = a.x + b.x;
        w[k].y     = a.y + b.y;
        w[k ^ m].x = a.x - b.x;
        w[k ^ m].y = a.y - b.y;
      }
    }
  }
}

__device__ __forceinline__ float softplus_f(float r) {
  return (r > 0.0f) ? (r + log1pf(__expf(-r))) : log1pf(__expf(r));
}

// Precompute g_tilde permuted into phase-B order:
// gt_perm[64*u + s] = g_tilde[256*(u>>2) + 4*s + (u&3)]
__global__ __launch_bounds__(256) void gt_perm_kernel(
    const float* __restrict__ g_mu, const float* __restrict__ g_rho,
    const float* __restrict__ eps, float* __restrict__ gt_perm)
{
  int idx = blockIdx.x * 256 + threadIdx.x;   // 0..4095
  int u = idx >> 6, s = idx & 63;
  int i = ((u >> 2) << 8) + (s << 2) + (u & 3);
  gt_perm[idx] = g_mu[i] + softplus_f(g_rho[i]) * eps[i];
}

// Element index i (12 bits): i = 256*j + 4*t + r  (j:4b reg, t:6b thread, r:2b reg)
// Phase A: FWHT over bits {j, r} in registers (thread t fixed).
// Phase B: FWHT over bits {t} in registers (thread u owns fixed (j,r)=u).
// LDS addr(i) = i + 4*(i>>8) = 260*j + 4*t + r  -> all accesses are
// thread-constant base + literal offset.
template <bool USE_WS>
__global__ __launch_bounds__(128) void whvi_kernel(
    const float* __restrict__ x,
    const float* __restrict__ s1,
    const float* __restrict__ s2,
    const float* __restrict__ gt_perm,   // USE_WS path
    const float* __restrict__ g_mu,      // fallback path
    const float* __restrict__ g_rho,
    const float* __restrict__ eps,
    float* __restrict__ out)
{
  __shared__ __align__(16) float lds[RPB * LROW];

  const int t = threadIdx.x & 63;
  const int wv = threadIdx.x >> 6;                 // row within block
  const size_t row = (size_t)blockIdx.x * RPB + wv;
  float* L = lds + wv * LROW;
  float2 w[32];

  // ---- load x * s2, phase-A layout; float4 coalesced (4 lanes per 64B line)
  const float4* x4  = (const float4*)x + row * (DDIM / 4);
  const float4* s24 = (const float4*)s2;
#pragma unroll
  for (int j = 0; j < 16; ++j) {
    float4 a = x4[64 * j + t];
    float4 b = s24[64 * j + t];
    w[2 * j].x     = a.x * b.x;
    w[2 * j].y     = a.y * b.y;
    w[2 * j + 1].x = a.z * b.z;
    w[2 * j + 1].y = a.w * b.w;
  }
  fwht64(w);                                       // FWHT1 bits {j, r}

  // ---- exchange A -> B (b128 writes, conflict-free) ----
#pragma unroll
  for (int j = 0; j < 16; ++j)
    *(float4*)&L[260 * j + 4 * t] =
        make_float4(w[2 * j].x, w[2 * j].y, w[2 * j + 1].x, w[2 * j + 1].y);
  __syncthreads();
  {
    const float* p = &L[260 * (t >> 2) + (t & 3)]; // base + 4*s words
#pragma unroll
    for (int k = 0; k < 32; ++k) {                 // ds_read2_b32, 2-way banks
      w[k].x = p[8 * k];
      w[k].y = p[8 * k + 4];
    }
  }
  fwht64(w);                                       // FWHT1 bits {t} -> done

  // ---- multiply by g_tilde (phase-B layout) ----
  if (USE_WS) {
    const float4* g4 = (const float4*)gt_perm + t * 16;
#pragma unroll
    for (int q = 0; q < 16; ++q) {
      float4 g = g4[q];
      w[2 * q].x     *= g.x;
      w[2 * q].y     *= g.y;
      w[2 * q + 1].x *= g.z;
      w[2 * q + 1].y *= g.w;
    }
  } else {
    const int base = 256 * (t >> 2) + (t & 3);
#pragma unroll
    for (int s = 0; s < 64; ++s) {
      int i = base + 4 * s;
      float g = g_mu[i] + softplus_f(g_rho[i]) * eps[i];
      ((float*)w)[s] *= g;   // w[s>>1].x/.y == v[s]
    }
  }

  fwht64(w);                                       // FWHT2 bits {t}

  // ---- exchange B -> A (same addresses each thread read: no extra barrier
  //      needed before writes beyond ensuring our own reads completed) ----
  __syncthreads();   // all B-reads done before any B-writes (LDS reuse)
  {
    float* p = &L[260 * (t >> 2) + (t & 3)];
#pragma unroll
    for (int k = 0; k < 32; ++k) {                 // ds_write2_b32
      p[8 * k]     = w[k].x;
      p[8 * k + 4] = w[k].y;
    }
  }
  __syncthreads();
#pragma unroll
  for (int j = 0; j < 16; ++j) {                   // b128 reads, conflict-free
    float4 a = *(const float4*)&L[260 * j + 4 * t];
    w[2 * j].x     = a.x;
    w[2 * j].y     = a.y;
    w[2 * j + 1].x = a.z;
    w[2 * j + 1].y = a.w;
  }
  fwht64(w);                                       // FWHT2 bits {j, r} -> done

  // ---- multiply by s1, store coalesced ----
  const float4* s14 = (const float4*)s1;
  float4* out4 = (float4*)out + row * (DDIM / 4);
#pragma unroll
  for (int j = 0; j < 16; ++j) {
    float4 b = s14[64 * j + t];
    out4[64 * j + t] = make_float4(w[2 * j].x * b.x, w[2 * j].y * b.y,
                                   w[2 * j + 1].x * b.z, w[2 * j + 1].y * b.w);
  }
}

extern "C" void kernel_launch(void* const* d_in, const int* in_sizes, int n_in,
                              void* d_out, int out_size, void* d_ws, size_t ws_size,
                              hipStream_t stream) {
  const float* x     = (const float*)d_in[0];
  const float* s1    = (const float*)d_in[1];
  const float* s2    = (const float*)d_in[2];
  const float* g_mu  = (const float*)d_in[3];
  const float* g_rho = (const float*)d_in[4];
  const float* eps   = (const float*)d_in[5];
  float* out = (float*)d_out;

  if (ws_size >= DDIM * sizeof(float)) {
    float* gt_perm = (float*)d_ws;
    gt_perm_kernel<<<DDIM / 256, 256, 0, stream>>>(g_mu, g_rho, eps, gt_perm);
    whvi_kernel<true><<<NTOK / RPB, 64 * RPB, 0, stream>>>(
        x, s1, s2, gt_perm, nullptr, nullptr, nullptr, out);
  } else {
    whvi_kernel<false><<<NTOK / RPB, 64 * RPB, 0, stream>>>(
        x, s1, s2, nullptr, g_mu, g_rho, eps, out);
  }
}

// Round 3
// 271.219 us; speedup vs baseline: 1.2838x; 1.0179x over previous
//
#include <hip/hip_runtime.h>
#include <math.h>

#define DDIM 4096
#define NTOK 8192
#define LROW 4160         // 16 j-blocks * 260 words; addr(i) = 260*j + 4*t + r

// FWHT over 64 elements held as float2 w[32].
__device__ __forceinline__ void fwht64(float2 w[32]) {
#pragma unroll
  for (int k = 0; k < 32; ++k) {
    float p = w[k].x, q = w[k].y;
    w[k].x = p + q;
    w[k].y = p - q;
  }
#pragma unroll
  for (int m = 1; m < 32; m <<= 1) {
#pragma unroll
    for (int k = 0; k < 32; ++k) {
      if ((k & m) == 0) {
        float2 a = w[k], b = w[k ^ m];
        w[k].x     = a.x + b.x;
        w[k].y     = a.y + b.y;
        w[k ^ m].x = a.x - b.x;
        w[k ^ m].y = a.y - b.y;
      }
    }
  }
}

__device__ __forceinline__ float softplus_f(float r) {
  return (r > 0.0f) ? (r + log1pf(__expf(-r))) : log1pf(__expf(r));
}

// gt_perm[64*u + s] = g_tilde[256*(u>>2) + 4*s + (u&3)]  (phase-B order)
__global__ __launch_bounds__(256) void gt_perm_kernel(
    const float* __restrict__ g_mu, const float* __restrict__ g_rho,
    const float* __restrict__ eps, float* __restrict__ gt_perm)
{
  int idx = blockIdx.x * 256 + threadIdx.x;   // 0..4095
  int u = idx >> 6, s = idx & 63;
  int i = ((u >> 2) << 8) + (s << 2) + (u & 3);
  gt_perm[idx] = g_mu[i] + softplus_f(g_rho[i]) * eps[i];
}

// Element index i (12 bits): i = 256*j + 4*t + r  (j:4b reg, t:6b lane, r:2b reg)
// Phase A: FWHT bits {j,r} in registers. Phase B: FWHT bits {t} in registers.
// One row per 64-thread block: LDS 16.6 KB -> 9 blocks/CU; single-wave
// barriers are cheap. launch_bounds caps VGPR at 128 (4 waves/SIMD budget).
template <bool USE_WS>
__global__ __launch_bounds__(64, 4) void whvi_kernel(
    const float* __restrict__ x,
    const float* __restrict__ s1,
    const float* __restrict__ s2,
    const float* __restrict__ gt_perm,   // USE_WS path
    const float* __restrict__ g_mu,      // fallback path
    const float* __restrict__ g_rho,
    const float* __restrict__ eps,
    float* __restrict__ out)
{
  __shared__ __align__(16) float L[LROW];

  const int t = threadIdx.x;              // 0..63
  const size_t row = (size_t)blockIdx.x;
  float2 w[32];

  // ---- load ALL x first (16 b128 in flight -> one HBM latency exposure) ----
  const float4* x4 = (const float4*)x + row * (DDIM / 4);
#pragma unroll
  for (int j = 0; j < 16; ++j) {
    float4 a = x4[64 * j + t];
    w[2 * j].x     = a.x;
    w[2 * j].y     = a.y;
    w[2 * j + 1].x = a.z;
    w[2 * j + 1].y = a.w;
  }
  // ---- multiply by s2 (L2-hot), streamed in 4x b128 chunks ----
  const float4* s24 = (const float4*)s2;
#pragma unroll
  for (int c = 0; c < 4; ++c) {
    float4 b0 = s24[64 * (4 * c + 0) + t];
    float4 b1 = s24[64 * (4 * c + 1) + t];
    float4 b2 = s24[64 * (4 * c + 2) + t];
    float4 b3 = s24[64 * (4 * c + 3) + t];
    int j = 4 * c;
    w[2*j+0].x *= b0.x; w[2*j+0].y *= b0.y; w[2*j+1].x *= b0.z; w[2*j+1].y *= b0.w;
    w[2*j+2].x *= b1.x; w[2*j+2].y *= b1.y; w[2*j+3].x *= b1.z; w[2*j+3].y *= b1.w;
    w[2*j+4].x *= b2.x; w[2*j+4].y *= b2.y; w[2*j+5].x *= b2.z; w[2*j+5].y *= b2.w;
    w[2*j+6].x *= b3.x; w[2*j+6].y *= b3.y; w[2*j+7].x *= b3.z; w[2*j+7].y *= b3.w;
  }
  fwht64(w);                                       // FWHT1 bits {j, r}

  // ---- exchange A -> B (b128 writes, conflict-free) ----
#pragma unroll
  for (int j = 0; j < 16; ++j)
    *(float4*)&L[260 * j + 4 * t] =
        make_float4(w[2 * j].x, w[2 * j].y, w[2 * j + 1].x, w[2 * j + 1].y);
  __syncthreads();
  {
    const float* p = &L[260 * (t >> 2) + (t & 3)];
#pragma unroll
    for (int k = 0; k < 32; ++k) {                 // ds_read2_b32, 2-way banks
      w[k].x = p[8 * k];
      w[k].y = p[8 * k + 4];
    }
  }
  fwht64(w);                                       // FWHT1 bits {t} -> done

  // ---- multiply by g_tilde (phase-B layout), streamed chunks ----
  if (USE_WS) {
    const float4* g4 = (const float4*)gt_perm + t * 16;
#pragma unroll
    for (int c = 0; c < 4; ++c) {
      float4 g0 = g4[4 * c + 0];
      float4 g1 = g4[4 * c + 1];
      float4 g2 = g4[4 * c + 2];
      float4 g3 = g4[4 * c + 3];
      int q = 4 * c;
      w[2*q+0].x *= g0.x; w[2*q+0].y *= g0.y; w[2*q+1].x *= g0.z; w[2*q+1].y *= g0.w;
      w[2*q+2].x *= g1.x; w[2*q+2].y *= g1.y; w[2*q+3].x *= g1.z; w[2*q+3].y *= g1.w;
      w[2*q+4].x *= g2.x; w[2*q+4].y *= g2.y; w[2*q+5].x *= g2.z; w[2*q+5].y *= g2.w;
      w[2*q+6].x *= g3.x; w[2*q+6].y *= g3.y; w[2*q+7].x *= g3.z; w[2*q+7].y *= g3.w;
    }
  } else {
    const int base = 256 * (t >> 2) + (t & 3);
#pragma unroll
    for (int s = 0; s < 64; ++s) {
      int i = base + 4 * s;
      float g = g_mu[i] + softplus_f(g_rho[i]) * eps[i];
      ((float*)w)[s] *= g;
    }
  }

  fwht64(w);                                       // FWHT2 bits {t}

  // ---- exchange B -> A (reuse LDS; barrier-protect both directions) ----
  __syncthreads();
  {
    float* p = &L[260 * (t >> 2) + (t & 3)];
#pragma unroll
    for (int k = 0; k < 32; ++k) {                 // ds_write2_b32
      p[8 * k]     = w[k].x;
      p[8 * k + 4] = w[k].y;
    }
  }
  __syncthreads();
#pragma unroll
  for (int j = 0; j < 16; ++j) {                   // b128 reads, conflict-free
    float4 a = *(const float4*)&L[260 * j + 4 * t];
    w[2 * j].x     = a.x;
    w[2 * j].y     = a.y;
    w[2 * j + 1].x = a.z;
    w[2 * j + 1].y = a.w;
  }
  fwht64(w);                                       // FWHT2 bits {j, r} -> done

  // ---- multiply by s1 (L2-hot), store coalesced ----
  const float4* s14 = (const float4*)s1;
  float4* out4 = (float4*)out + row * (DDIM / 4);
#pragma unroll
  for (int j = 0; j < 16; ++j) {
    float4 b = s14[64 * j + t];
    out4[64 * j + t] = make_float4(w[2 * j].x * b.x, w[2 * j].y * b.y,
                                   w[2 * j + 1].x * b.z, w[2 * j + 1].y * b.w);
  }
}

extern "C" void kernel_launch(void* const* d_in, const int* in_sizes, int n_in,
                              void* d_out, int out_size, void* d_ws, size_t ws_size,
                              hipStream_t stream) {
  const float* x     = (const float*)d_in[0];
  const float* s1    = (const float*)d_in[1];
  const float* s2    = (const float*)d_in[2];
  const float* g_mu  = (const float*)d_in[3];
  const float* g_rho = (const float*)d_in[4];
  const float* eps   = (const float*)d_in[5];
  float* out = (float*)d_out;

  if (ws_size >= DDIM * sizeof(float)) {
    float* gt_perm = (float*)d_ws;
    gt_perm_kernel<<<DDIM / 256, 256, 0, stream>>>(g_mu, g_rho, eps, gt_perm);
    whvi_kernel<true><<<NTOK, 64, 0, stream>>>(
        x, s1, s2, gt_perm, nullptr, nullptr, nullptr, out);
  } else {
    whvi_kernel<false><<<NTOK, 64, 0, stream>>>(
        x, s1, s2, nullptr, g_mu, g_rho, eps, out);
  }
}